// Round 15
// baseline (292.400 us; speedup 1.0000x reference)
//
#include <hip/hip_runtime.h>
#include <math.h>

// B=16, P=4096, D=512, G=64, N_IMGS=5000, TEMP=0.01
// M = 65536, K = 512, fused N = 1536 (q|k|v). GEMM outputs bf16.
// q in d_out interleaved: row n at elem offset n*1024 (first 512 used);
// k/v interleaved in one ws buffer: row n = [k(512) | v(512)], stride 1024.
// (r14 core = r10 GEMM + nontemporal sampler; best measured 287.6 us.)

typedef __attribute__((ext_vector_type(8))) short s16x8;   // 8 bf16 (4 VGPRs)
typedef __attribute__((ext_vector_type(4))) float f32x4;
typedef __attribute__((ext_vector_type(4))) unsigned int u32x4;

__device__ __forceinline__ unsigned short f2bf_u(unsigned u) {
    u += 0x7FFFu + ((u >> 16) & 1u);   // RNE on raw f32 bits
    return (unsigned short)(u >> 16);
}

__device__ __forceinline__ unsigned short f2bf(float f) {
    return f2bf_u(__float_as_uint(f));
}

__device__ __forceinline__ void gload_lds16(const void* g, void* l) {
    __builtin_amdgcn_global_load_lds(
        (const __attribute__((address_space(1))) unsigned int*)g,
        (__attribute__((address_space(3))) unsigned int*)l, 16, 0, 0);
}

// ---------- fused fp32 -> bf16 conversion: x then Wq|Wk|Wv ----------
// Grid-stride (2048 blocks), nontemporal loads: x/W are read-once streams.
__global__ __launch_bounds__(256) void cvt_all(
    const float* __restrict__ x, const float* __restrict__ Wq,
    const float* __restrict__ Wk, const float* __restrict__ Wv,
    unsigned short* __restrict__ xbf, unsigned short* __restrict__ wbf)
{
    const int NTOT = 4194304 + 98304;       // 8-elem groups: x then W
    for (int i = blockIdx.x * 256 + threadIdx.x; i < NTOT; i += 2048 * 256) {
        const float* src;
        unsigned short* dst;
        size_t off;
        if (i < 4194304) {                  // x: 65536*512 / 8
            src = x; dst = xbf; off = (size_t)i;
        } else {
            int t = i - 4194304;            // 0 .. 98303
            int w = t >> 15;                // 0..2
            off = (size_t)(t & 32767);
            src = (w == 0) ? Wq : (w == 1 ? Wk : Wv);
            dst = wbf + (size_t)w * 512 * 512;
        }
        const u32x4* s = (const u32x4*)src + 2 * off;
        u32x4 a = __builtin_nontemporal_load(s);
        u32x4 b = __builtin_nontemporal_load(s + 1);
        uint4 o;
        o.x = (unsigned)f2bf_u(a[0]) | ((unsigned)f2bf_u(a[1]) << 16);
        o.y = (unsigned)f2bf_u(a[2]) | ((unsigned)f2bf_u(a[3]) << 16);
        o.z = (unsigned)f2bf_u(b[0]) | ((unsigned)f2bf_u(b[1]) << 16);
        o.w = (unsigned)f2bf_u(b[2]) | ((unsigned)f2bf_u(b[3]) << 16);
        ((uint4*)dst)[off] = o;
    }
}

// ---------- fused QKV GEMM (r10 core + relaxed phase-1 lgkm wait) ----------
// 256x256 tile, BK=32, 512 threads (8 waves 2x4), per-wave 128x64 (acc[8][4]).
// LDS: 4-ring of 32 KiB K-tile buffers = 128 KiB. Stage T+3, vmcnt(8).
// Phase 1 waits lgkmcnt(4): afB[4] (consumed in phase 2) stays in flight
// under the first MFMA cluster; compiler auto-inserts the precise wait
// before afB's first use (C++ loads -> deps are compiler-visible).
template<int T, int NVM, bool STAGE>
__device__ __forceinline__ void tile_step(
    char* ldsc, const unsigned short* aP, const unsigned short* bP,
    int tid, int abase, int bbase, f32x4 (&acc)[8][4])
{
    asm volatile("s_waitcnt vmcnt(%0)" :: "i"(NVM) : "memory");
    __builtin_amdgcn_s_barrier();            // tile T landed; buf[(T+3)&3] free
    __builtin_amdgcn_sched_barrier(0);
    const char* lp = ldsc + (T & 3) * 32768;
    s16x8 bfr[4], afA[4], afB[4];
    #pragma unroll
    for (int j = 0; j < 4; ++j) bfr[j] = *(const s16x8*)(lp + bbase + j * 256);
    #pragma unroll
    for (int u = 0; u < 4; ++u) afA[u] = *(const s16x8*)(lp + abase + u * 256);
    #pragma unroll
    for (int u = 0; u < 4; ++u) afB[u] = *(const s16x8*)(lp + abase + 1024 + u * 256);
    if (STAGE) {                             // A-half of tile T+3
        const int bo = ((T + 3) & 3) * 32768;
        gload_lds16(aP + (T + 3) * 32,      ldsc + bo + tid * 16);
        gload_lds16(aP + (T + 3) * 32 + 16, ldsc + bo + 8192 + tid * 16);
    }
    __builtin_amdgcn_s_barrier();
    asm volatile("s_waitcnt lgkmcnt(4)");
    __builtin_amdgcn_sched_barrier(0);
    __builtin_amdgcn_s_setprio(1);
    #pragma unroll
    for (int u = 0; u < 4; ++u)
        #pragma unroll
        for (int j = 0; j < 4; ++j)
            acc[u][j] = __builtin_amdgcn_mfma_f32_16x16x32_bf16(
                bfr[j], afA[u], acc[u][j], 0, 0, 0);   // swapped operands
    __builtin_amdgcn_s_setprio(0);
    __builtin_amdgcn_s_barrier();
    __builtin_amdgcn_sched_barrier(0);
    if (STAGE) {                             // B-half of tile T+3
        const int bo = ((T + 3) & 3) * 32768;
        gload_lds16(bP + (T + 3) * 32,      ldsc + bo + 16384 + tid * 16);
        gload_lds16(bP + (T + 3) * 32 + 16, ldsc + bo + 24576 + tid * 16);
    }
    __builtin_amdgcn_s_setprio(1);
    #pragma unroll
    for (int u = 0; u < 4; ++u)
        #pragma unroll
        for (int j = 0; j < 4; ++j)
            acc[4 + u][j] = __builtin_amdgcn_mfma_f32_16x16x32_bf16(
                bfr[j], afB[u], acc[4 + u][j], 0, 0, 0);
    __builtin_amdgcn_s_setprio(0);
}

__global__ __launch_bounds__(512, 1) void qkv_gemm(
    const unsigned short* __restrict__ xbf,   // (65536,512) bf16
    const unsigned short* __restrict__ wbf,   // (1536,512) bf16 (Wq|Wk|Wv)
    const float* __restrict__ bq, const float* __restrict__ bk,
    const float* __restrict__ bv,
    unsigned short* __restrict__ qbf,         // d_out, row stride 1024 elems
    unsigned short* __restrict__ kvbf)        // (65536,1024): [k|v] per row
{
    __shared__ __align__(16) short lds[4][16384];   // 128 KiB ring / bounce

    const int tid  = threadIdx.x;
    const int lane = tid & 63, wid = tid >> 6;
    const int wr = wid >> 2, wc = wid & 3;    // 2 (m) x 4 (n) waves

    // Bijective XCD swizzle: 1536 blocks = 8 XCDs * 192.
    const int bid = blockIdx.x;
    const int wgid = (bid & 7) * 192 + (bid >> 3);
    const int mt = wgid / 6, nt = wgid % 6;
    const int m0 = mt * 256, n0 = nt * 256;

    const int srow = tid & 255;
    const unsigned short* aP = xbf + (size_t)(m0 + srow) * 512 + (tid >> 8) * 8;
    const unsigned short* bP = wbf + (size_t)(n0 + srow) * 512 + (tid >> 8) * 8;
    char* ldsc = (char*)lds;

    f32x4 acc[8][4] = {};

    const int abase = (lane >> 4) * 4096 + (wr * 128 + (lane & 15)) * 16;
    const int bbase = 16384 + (lane >> 4) * 4096 + (wc * 64 + (lane & 15)) * 16;

    // prologue: stage tiles 0,1,2
    #pragma unroll
    for (int t = 0; t < 3; ++t) {
        const int bo = t * 32768;
        gload_lds16(aP + t * 32,      ldsc + bo + tid * 16);
        gload_lds16(aP + t * 32 + 16, ldsc + bo + 8192 + tid * 16);
        gload_lds16(bP + t * 32,      ldsc + bo + 16384 + tid * 16);
        gload_lds16(bP + t * 32 + 16, ldsc + bo + 24576 + tid * 16);
    }

    tile_step< 0, 8, true >(ldsc, aP, bP, tid, abase, bbase, acc);
    tile_step< 1, 8, true >(ldsc, aP, bP, tid, abase, bbase, acc);
    tile_step< 2, 8, true >(ldsc, aP, bP, tid, abase, bbase, acc);
    tile_step< 3, 8, true >(ldsc, aP, bP, tid, abase, bbase, acc);
    tile_step< 4, 8, true >(ldsc, aP, bP, tid, abase, bbase, acc);
    tile_step< 5, 8, true >(ldsc, aP, bP, tid, abase, bbase, acc);
    tile_step< 6, 8, true >(ldsc, aP, bP, tid, abase, bbase, acc);
    tile_step< 7, 8, true >(ldsc, aP, bP, tid, abase, bbase, acc);
    tile_step< 8, 8, true >(ldsc, aP, bP, tid, abase, bbase, acc);
    tile_step< 9, 8, true >(ldsc, aP, bP, tid, abase, bbase, acc);
    tile_step<10, 8, true >(ldsc, aP, bP, tid, abase, bbase, acc);
    tile_step<11, 8, true >(ldsc, aP, bP, tid, abase, bbase, acc);
    tile_step<12, 8, true >(ldsc, aP, bP, tid, abase, bbase, acc);
    tile_step<13, 8, false>(ldsc, aP, bP, tid, abase, bbase, acc);
    tile_step<14, 4, false>(ldsc, aP, bP, tid, abase, bbase, acc);
    tile_step<15, 0, false>(ldsc, aP, bP, tid, abase, bbase, acc);

    // ---- Epilogue: swizzled full-tile LDS bounce (256x256 bf16 = 128 KiB) ----
    const int sel = nt >> 1;                   // 0=q, 1=k, 2=v
    const float* bias = sel == 0 ? bq : (sel == 1 ? bk : bv);
    const int rowl = wr * 128 + (lane & 15);          // + i*16
    const int coll = wc * 64 + ((lane >> 4) << 2);    // + j*16
    const int colg = (n0 & 511) + coll;

    __syncthreads();                           // all K-loop LDS reads done
    #pragma unroll
    for (int j = 0; j < 4; ++j) {
        const float4 b4 = *(const float4*)&bias[colg + j * 16];
        #pragma unroll
        for (int i = 0; i < 8; ++i) {
            const int row = rowl + i * 16;
            const int cb  = (coll + j * 16) * 2;       // col byte 0..511
            const int byt = row * 512 + (((cb & ~15) ^ ((row & 7) << 4)) | (cb & 15));
            uint2 o;
            o.x = (unsigned)f2bf(acc[i][j][0] + b4.x)
                | ((unsigned)f2bf(acc[i][j][1] + b4.y) << 16);
            o.y = (unsigned)f2bf(acc[i][j][2] + b4.z)
                | ((unsigned)f2bf(acc[i][j][3] + b4.w) << 16);
            *(uint2*)(ldsc + byt) = o;
        }
    }
    __syncthreads();
    {
        unsigned short* dst = (sel == 0) ? qbf : kvbf;
        const int voff = (sel == 2) ? 512 : 0;   // v goes in the upper half
        const int rr = tid >> 5;        // 0..15
        const int cc = tid & 31;        // 16 B chunk within 512 B row
        #pragma unroll
        for (int s = 0; s < 16; ++s) {
            const int r = s * 16 + rr;
            const int byt = r * 512 + ((cc * 16) ^ ((r & 7) << 4));
            uint4 d = *(const uint4*)(ldsc + byt);
            *(uint4*)&dst[(size_t)(m0 + r) * 1024 + voff + (n0 & 511) + cc * 8] = d;
        }
    }
}

// ---------- grid-sample + gated attention ----------
__global__ __launch_bounds__(256) void sample_attn(
    float* __restrict__ qo,                 // d_out: bf16 q in (stride 1024), f32 out
    const unsigned short* __restrict__ kvbf,// (B,P,1024) bf16: [k|v] per row
    const float* __restrict__ avgs,         // (N_IMGS,2,P)
    const float* __restrict__ stds,
    const float* __restrict__ nx,           // (B,1,P)
    const float* __restrict__ ny,
    const int* __restrict__ img_ids)
{
    const int lane = threadIdx.x & 63;
    const int wid  = threadIdx.x >> 6;
    const int point = (blockIdx.x << 2) + wid;
    const int b = point >> 12;
    const int n = point & 4095;
    const int g1 = n >> 6, g2 = n & 63;
    const int f0 = g1 * 128 + g2 * 2;
    const int id = img_ids[b];

    float g[2];
    #pragma unroll
    for (int c = 0; c < 2; ++c) {
        int f = f0 + c;
        int ch = f >> 12;
        int p  = f & 4095;
        float noise = ch ? ny[(size_t)b * 4096 + p] : nx[(size_t)b * 4096 + p];
        size_t o = ((size_t)id * 2 + ch) * 4096 + p;
        g[c] = tanhf((noise + avgs[o]) * stds[o]);
    }

    float ix = (g[0] + 1.0f) * 32.0f - 0.5f;
    float iy = (g[1] + 1.0f) * 32.0f - 0.5f;
    float fx0 = floorf(ix), fy0 = floorf(iy);
    float wx1 = ix - fx0, wx0 = 1.0f - wx1;
    float wy1 = iy - fy0, wy0 = 1.0f - wy1;
    int x0 = (int)fx0, y0 = (int)fy0;
    int x1 = x0 + 1, y1 = y0 + 1;
    bool vx0 = (x0 >= 0) & (x0 < 64), vx1 = (x1 >= 0) & (x1 < 64);
    bool vy0 = (y0 >= 0) & (y0 < 64), vy1 = (y1 >= 0) & (y1 < 64);
    float w00 = (vx0 & vy0) ? wx0 * wy0 : 0.0f;
    float w10 = (vx1 & vy0) ? wx1 * wy0 : 0.0f;
    float w01 = (vx0 & vy1) ? wx0 * wy1 : 0.0f;
    float w11 = (vx1 & vy1) ? wx1 * wy1 : 0.0f;
    int cx0 = min(max(x0, 0), 63), cx1 = min(max(x1, 0), 63);
    int cy0 = min(max(y0, 0), 63), cy1 = min(max(y1, 0), 63);

    const size_t base = (size_t)b * 4096;
    const size_t r00 = (base + (size_t)(cy0 * 64 + cx0)) * 1024;
    const size_t r10 = (base + (size_t)(cy0 * 64 + cx1)) * 1024;
    const size_t r01 = (base + (size_t)(cy1 * 64 + cx0)) * 1024;
    const size_t r11 = (base + (size_t)(cy1 * 64 + cx1)) * 1024;

    const int c = lane * 8;

    // q row (bf16, interleaved in d_out at elem stride 1024) — streamed once
    const unsigned short* qrowb =
        (const unsigned short*)qo + ((size_t)(b * 4096 + n)) * 1024;
    u32x4 qu = __builtin_nontemporal_load((const u32x4*)(qrowb + c));
    float qv[8];
    #pragma unroll
    for (int t = 0; t < 4; ++t) {
        qv[2 * t]     = __uint_as_float(qu[t] << 16);
        qv[2 * t + 1] = __uint_as_float(qu[t] & 0xFFFF0000u);
    }

    float sk[8], sv[8];
    {
        uint4 u00k = *(const uint4*)(kvbf + r00 + c);
        uint4 u10k = *(const uint4*)(kvbf + r10 + c);
        uint4 u01k = *(const uint4*)(kvbf + r01 + c);
        uint4 u11k = *(const uint4*)(kvbf + r11 + c);
        uint4 u00v = *(const uint4*)(kvbf + r00 + 512 + c);
        uint4 u10v = *(const uint4*)(kvbf + r10 + 512 + c);
        uint4 u01v = *(const uint4*)(kvbf + r01 + 512 + c);
        uint4 u11v = *(const uint4*)(kvbf + r11 + 512 + c);
        const unsigned* p00k = (const unsigned*)&u00k;
        const unsigned* p10k = (const unsigned*)&u10k;
        const unsigned* p01k = (const unsigned*)&u01k;
        const unsigned* p11k = (const unsigned*)&u11k;
        const unsigned* p00v = (const unsigned*)&u00v;
        const unsigned* p10v = (const unsigned*)&u10v;
        const unsigned* p01v = (const unsigned*)&u01v;
        const unsigned* p11v = (const unsigned*)&u11v;
        #pragma unroll
        for (int t = 0; t < 4; ++t) {
            float a00 = __uint_as_float(p00k[t] << 16);
            float b00 = __uint_as_float(p00k[t] & 0xFFFF0000u);
            float a10 = __uint_as_float(p10k[t] << 16);
            float b10 = __uint_as_float(p10k[t] & 0xFFFF0000u);
            float a01 = __uint_as_float(p01k[t] << 16);
            float b01 = __uint_as_float(p01k[t] & 0xFFFF0000u);
            float a11 = __uint_as_float(p11k[t] << 16);
            float b11 = __uint_as_float(p11k[t] & 0xFFFF0000u);
            sk[2 * t]     = w00 * a00 + w10 * a10 + w01 * a01 + w11 * a11;
            sk[2 * t + 1] = w00 * b00 + w10 * b10 + w01 * b01 + w11 * b11;
            a00 = __uint_as_float(p00v[t] << 16);
            b00 = __uint_as_float(p00v[t] & 0xFFFF0000u);
            a10 = __uint_as_float(p10v[t] << 16);
            b10 = __uint_as_float(p10v[t] & 0xFFFF0000u);
            a01 = __uint_as_float(p01v[t] << 16);
            b01 = __uint_as_float(p01v[t] & 0xFFFF0000u);
            a11 = __uint_as_float(p11v[t] << 16);
            b11 = __uint_as_float(p11v[t] & 0xFFFF0000u);
            sv[2 * t]     = w00 * a00 + w10 * a10 + w01 * a01 + w11 * a11;
            sv[2 * t + 1] = w00 * b00 + w10 * b10 + w01 * b01 + w11 * b11;
        }
    }

    float score = 0.0f;
    #pragma unroll
    for (int t = 0; t < 8; ++t) score += qv[t] * sk[t];
    #pragma unroll
    for (int off = 32; off > 0; off >>= 1)
        score += __shfl_xor(score, off);

    const float sig = 1.0f / (1.0f + expf(-0.01f * score));
    float* orow = qo + ((size_t)(b * 4096 + n)) * 512;
    f32x4 oA, oB;
    oA[0] = sig * sv[0]; oA[1] = sig * sv[1]; oA[2] = sig * sv[2]; oA[3] = sig * sv[3];
    oB[0] = sig * sv[4]; oB[1] = sig * sv[5]; oB[2] = sig * sv[6]; oB[3] = sig * sv[7];
    // output is never re-read: nontemporal stores keep L2/L3 for kv gathers
    __builtin_nontemporal_store(oA, (f32x4*)(orow + c));
    __builtin_nontemporal_store(oB, (f32x4*)(orow + c + 4));
}

extern "C" void kernel_launch(void* const* d_in, const int* in_sizes, int n_in,
                              void* d_out, int out_size, void* d_ws, size_t ws_size,
                              hipStream_t stream)
{
    const float* x    = (const float*)d_in[0];
    const float* Wq   = (const float*)d_in[1];
    const float* bq   = (const float*)d_in[2];
    const float* Wk   = (const float*)d_in[3];
    const float* bk   = (const float*)d_in[4];
    const float* Wv   = (const float*)d_in[5];
    const float* bv   = (const float*)d_in[6];
    const float* avgs = (const float*)d_in[7];
    const float* stds = (const float*)d_in[8];
    const float* nx   = (const float*)d_in[9];
    const float* ny   = (const float*)d_in[10];
    const int* img_ids = (const int*)d_in[11];

    float* out = (float*)d_out;

    unsigned short* xbf  = (unsigned short*)d_ws;           // 67.1 MB
    unsigned short* wbf  = xbf + (size_t)65536 * 512;       // 1.57 MB
    unsigned short* kvbf = wbf + (size_t)1536 * 512;        // 134 MB ([k|v] rows)

    cvt_all<<<2048, 256, 0, stream>>>(x, Wq, Wk, Wv, xbf, wbf);

    qkv_gemm<<<1536, 512, 0, stream>>>(xbf, wbf, bq, bk, bv,
                                       (unsigned short*)d_out, kvbf);

    sample_attn<<<16384, 256, 0, stream>>>(out, kvbf, avgs, stds, nx, ny, img_ids);
}

// Round 16
// 287.366 us; speedup vs baseline: 1.0175x; 1.0175x over previous
//
#include <hip/hip_runtime.h>
#include <math.h>

// B=16, P=4096, D=512, G=64, N_IMGS=5000, TEMP=0.01
// M = 65536, K = 512, fused N = 1536 (q|k|v). GEMM outputs bf16.
// q in d_out interleaved: row n at elem offset n*1024 (first 512 used);
// k/v interleaved in one ws buffer: row n = [k(512) | v(512)], stride 1024.
// (r14 exact revert — best measured: 287.6 us total, GEMM 182.4 us.)

typedef __attribute__((ext_vector_type(8))) short s16x8;   // 8 bf16 (4 VGPRs)
typedef __attribute__((ext_vector_type(4))) float f32x4;
typedef __attribute__((ext_vector_type(4))) unsigned int u32x4;

__device__ __forceinline__ unsigned short f2bf(float f) {
    unsigned u = __float_as_uint(f);
    u += 0x7FFFu + ((u >> 16) & 1u);   // RNE
    return (unsigned short)(u >> 16);
}

__device__ __forceinline__ void gload_lds16(const void* g, void* l) {
    __builtin_amdgcn_global_load_lds(
        (const __attribute__((address_space(1))) unsigned int*)g,
        (__attribute__((address_space(3))) unsigned int*)l, 16, 0, 0);
}

// ---------- fused fp32 -> bf16 conversion: x then Wq|Wk|Wv ----------
__global__ __launch_bounds__(256) void cvt_all(
    const float* __restrict__ x, const float* __restrict__ Wq,
    const float* __restrict__ Wk, const float* __restrict__ Wv,
    unsigned short* __restrict__ xbf, unsigned short* __restrict__ wbf)
{
    const int i = blockIdx.x * 256 + threadIdx.x;   // 8-elem group index
    const float* src;
    unsigned short* dst;
    size_t off;
    if (i < 4194304) {                 // x: 65536*512 / 8
        src = x; dst = xbf; off = (size_t)i;
    } else {
        int t = i - 4194304;           // 0 .. 98303
        int w = t >> 15;               // 0..2
        off = (size_t)(t & 32767);
        src = (w == 0) ? Wq : (w == 1 ? Wk : Wv);
        dst = wbf + (size_t)w * 512 * 512;
    }
    const float4* s = (const float4*)src + 2 * off;
    float4 a = s[0], b = s[1];
    uint4 o;
    o.x = (unsigned)f2bf(a.x) | ((unsigned)f2bf(a.y) << 16);
    o.y = (unsigned)f2bf(a.z) | ((unsigned)f2bf(a.w) << 16);
    o.z = (unsigned)f2bf(b.x) | ((unsigned)f2bf(b.y) << 16);
    o.w = (unsigned)f2bf(b.z) | ((unsigned)f2bf(b.w) << 16);
    ((uint4*)dst)[off] = o;
}

// ---------- fused QKV GEMM (r10 core) ----------
// 256x256 tile, BK=32, 512 threads (8 waves 2x4), per-wave 128x64 (acc[8][4]).
// LDS: 4-ring of 32 KiB K-tile buffers = 128 KiB. Stage T+3, vmcnt(8).
// r8 lockstep phase-split skeleton with all 12 ds_reads hoisted to phase 1.
template<int T, int NVM, bool STAGE>
__device__ __forceinline__ void tile_step(
    char* ldsc, const unsigned short* aP, const unsigned short* bP,
    int tid, int abase, int bbase, f32x4 (&acc)[8][4])
{
    asm volatile("s_waitcnt vmcnt(%0)" :: "i"(NVM) : "memory");
    __builtin_amdgcn_s_barrier();            // tile T landed; buf[(T+3)&3] free
    __builtin_amdgcn_sched_barrier(0);
    const char* lp = ldsc + (T & 3) * 32768;
    s16x8 bfr[4], afA[4], afB[4];
    #pragma unroll
    for (int j = 0; j < 4; ++j) bfr[j] = *(const s16x8*)(lp + bbase + j * 256);
    #pragma unroll
    for (int u = 0; u < 4; ++u) afA[u] = *(const s16x8*)(lp + abase + u * 256);
    #pragma unroll
    for (int u = 0; u < 4; ++u) afB[u] = *(const s16x8*)(lp + abase + 1024 + u * 256);
    if (STAGE) {                             // A-half of tile T+3
        const int bo = ((T + 3) & 3) * 32768;
        gload_lds16(aP + (T + 3) * 32,      ldsc + bo + tid * 16);
        gload_lds16(aP + (T + 3) * 32 + 16, ldsc + bo + 8192 + tid * 16);
    }
    __builtin_amdgcn_s_barrier();
    asm volatile("s_waitcnt lgkmcnt(0)");
    __builtin_amdgcn_sched_barrier(0);
    __builtin_amdgcn_s_setprio(1);
    #pragma unroll
    for (int u = 0; u < 4; ++u)
        #pragma unroll
        for (int j = 0; j < 4; ++j)
            acc[u][j] = __builtin_amdgcn_mfma_f32_16x16x32_bf16(
                bfr[j], afA[u], acc[u][j], 0, 0, 0);   // swapped operands
    __builtin_amdgcn_s_setprio(0);
    __builtin_amdgcn_s_barrier();
    __builtin_amdgcn_sched_barrier(0);
    if (STAGE) {                             // B-half of tile T+3
        const int bo = ((T + 3) & 3) * 32768;
        gload_lds16(bP + (T + 3) * 32,      ldsc + bo + 16384 + tid * 16);
        gload_lds16(bP + (T + 3) * 32 + 16, ldsc + bo + 24576 + tid * 16);
    }
    __builtin_amdgcn_s_setprio(1);
    #pragma unroll
    for (int u = 0; u < 4; ++u)
        #pragma unroll
        for (int j = 0; j < 4; ++j)
            acc[4 + u][j] = __builtin_amdgcn_mfma_f32_16x16x32_bf16(
                bfr[j], afB[u], acc[4 + u][j], 0, 0, 0);
    __builtin_amdgcn_s_setprio(0);
}

__global__ __launch_bounds__(512, 1) void qkv_gemm(
    const unsigned short* __restrict__ xbf,   // (65536,512) bf16
    const unsigned short* __restrict__ wbf,   // (1536,512) bf16 (Wq|Wk|Wv)
    const float* __restrict__ bq, const float* __restrict__ bk,
    const float* __restrict__ bv,
    unsigned short* __restrict__ qbf,         // d_out, row stride 1024 elems
    unsigned short* __restrict__ kvbf)        // (65536,1024): [k|v] per row
{
    __shared__ __align__(16) short lds[4][16384];   // 128 KiB ring / bounce

    const int tid  = threadIdx.x;
    const int lane = tid & 63, wid = tid >> 6;
    const int wr = wid >> 2, wc = wid & 3;    // 2 (m) x 4 (n) waves

    // Bijective XCD swizzle: 1536 blocks = 8 XCDs * 192.
    const int bid = blockIdx.x;
    const int wgid = (bid & 7) * 192 + (bid >> 3);
    const int mt = wgid / 6, nt = wgid % 6;
    const int m0 = mt * 256, n0 = nt * 256;

    const int srow = tid & 255;
    const unsigned short* aP = xbf + (size_t)(m0 + srow) * 512 + (tid >> 8) * 8;
    const unsigned short* bP = wbf + (size_t)(n0 + srow) * 512 + (tid >> 8) * 8;
    char* ldsc = (char*)lds;

    f32x4 acc[8][4] = {};

    const int abase = (lane >> 4) * 4096 + (wr * 128 + (lane & 15)) * 16;
    const int bbase = 16384 + (lane >> 4) * 4096 + (wc * 64 + (lane & 15)) * 16;

    // prologue: stage tiles 0,1,2
    #pragma unroll
    for (int t = 0; t < 3; ++t) {
        const int bo = t * 32768;
        gload_lds16(aP + t * 32,      ldsc + bo + tid * 16);
        gload_lds16(aP + t * 32 + 16, ldsc + bo + 8192 + tid * 16);
        gload_lds16(bP + t * 32,      ldsc + bo + 16384 + tid * 16);
        gload_lds16(bP + t * 32 + 16, ldsc + bo + 24576 + tid * 16);
    }

    tile_step< 0, 8, true >(ldsc, aP, bP, tid, abase, bbase, acc);
    tile_step< 1, 8, true >(ldsc, aP, bP, tid, abase, bbase, acc);
    tile_step< 2, 8, true >(ldsc, aP, bP, tid, abase, bbase, acc);
    tile_step< 3, 8, true >(ldsc, aP, bP, tid, abase, bbase, acc);
    tile_step< 4, 8, true >(ldsc, aP, bP, tid, abase, bbase, acc);
    tile_step< 5, 8, true >(ldsc, aP, bP, tid, abase, bbase, acc);
    tile_step< 6, 8, true >(ldsc, aP, bP, tid, abase, bbase, acc);
    tile_step< 7, 8, true >(ldsc, aP, bP, tid, abase, bbase, acc);
    tile_step< 8, 8, true >(ldsc, aP, bP, tid, abase, bbase, acc);
    tile_step< 9, 8, true >(ldsc, aP, bP, tid, abase, bbase, acc);
    tile_step<10, 8, true >(ldsc, aP, bP, tid, abase, bbase, acc);
    tile_step<11, 8, true >(ldsc, aP, bP, tid, abase, bbase, acc);
    tile_step<12, 8, true >(ldsc, aP, bP, tid, abase, bbase, acc);
    tile_step<13, 8, false>(ldsc, aP, bP, tid, abase, bbase, acc);
    tile_step<14, 4, false>(ldsc, aP, bP, tid, abase, bbase, acc);
    tile_step<15, 0, false>(ldsc, aP, bP, tid, abase, bbase, acc);

    // ---- Epilogue: swizzled full-tile LDS bounce (256x256 bf16 = 128 KiB) ----
    const int sel = nt >> 1;                   // 0=q, 1=k, 2=v
    const float* bias = sel == 0 ? bq : (sel == 1 ? bk : bv);
    const int rowl = wr * 128 + (lane & 15);          // + i*16
    const int coll = wc * 64 + ((lane >> 4) << 2);    // + j*16
    const int colg = (n0 & 511) + coll;

    __syncthreads();                           // all K-loop LDS reads done
    #pragma unroll
    for (int j = 0; j < 4; ++j) {
        const float4 b4 = *(const float4*)&bias[colg + j * 16];
        #pragma unroll
        for (int i = 0; i < 8; ++i) {
            const int row = rowl + i * 16;
            const int cb  = (coll + j * 16) * 2;       // col byte 0..511
            const int byt = row * 512 + (((cb & ~15) ^ ((row & 7) << 4)) | (cb & 15));
            uint2 o;
            o.x = (unsigned)f2bf(acc[i][j][0] + b4.x)
                | ((unsigned)f2bf(acc[i][j][1] + b4.y) << 16);
            o.y = (unsigned)f2bf(acc[i][j][2] + b4.z)
                | ((unsigned)f2bf(acc[i][j][3] + b4.w) << 16);
            *(uint2*)(ldsc + byt) = o;
        }
    }
    __syncthreads();
    {
        unsigned short* dst = (sel == 0) ? qbf : kvbf;
        const int voff = (sel == 2) ? 512 : 0;   // v goes in the upper half
        const int rr = tid >> 5;        // 0..15
        const int cc = tid & 31;        // 16 B chunk within 512 B row
        #pragma unroll
        for (int s = 0; s < 16; ++s) {
            const int r = s * 16 + rr;
            const int byt = r * 512 + ((cc * 16) ^ ((r & 7) << 4));
            uint4 d = *(const uint4*)(ldsc + byt);
            *(uint4*)&dst[(size_t)(m0 + r) * 1024 + voff + (n0 & 511) + cc * 8] = d;
        }
    }
}

// ---------- grid-sample + gated attention ----------
__global__ __launch_bounds__(256) void sample_attn(
    float* __restrict__ qo,                 // d_out: bf16 q in (stride 1024), f32 out
    const unsigned short* __restrict__ kvbf,// (B,P,1024) bf16: [k|v] per row
    const float* __restrict__ avgs,         // (N_IMGS,2,P)
    const float* __restrict__ stds,
    const float* __restrict__ nx,           // (B,1,P)
    const float* __restrict__ ny,
    const int* __restrict__ img_ids)
{
    const int lane = threadIdx.x & 63;
    const int wid  = threadIdx.x >> 6;
    const int point = (blockIdx.x << 2) + wid;
    const int b = point >> 12;
    const int n = point & 4095;
    const int g1 = n >> 6, g2 = n & 63;
    const int f0 = g1 * 128 + g2 * 2;
    const int id = img_ids[b];

    float g[2];
    #pragma unroll
    for (int c = 0; c < 2; ++c) {
        int f = f0 + c;
        int ch = f >> 12;
        int p  = f & 4095;
        float noise = ch ? ny[(size_t)b * 4096 + p] : nx[(size_t)b * 4096 + p];
        size_t o = ((size_t)id * 2 + ch) * 4096 + p;
        g[c] = tanhf((noise + avgs[o]) * stds[o]);
    }

    float ix = (g[0] + 1.0f) * 32.0f - 0.5f;
    float iy = (g[1] + 1.0f) * 32.0f - 0.5f;
    float fx0 = floorf(ix), fy0 = floorf(iy);
    float wx1 = ix - fx0, wx0 = 1.0f - wx1;
    float wy1 = iy - fy0, wy0 = 1.0f - wy1;
    int x0 = (int)fx0, y0 = (int)fy0;
    int x1 = x0 + 1, y1 = y0 + 1;
    bool vx0 = (x0 >= 0) & (x0 < 64), vx1 = (x1 >= 0) & (x1 < 64);
    bool vy0 = (y0 >= 0) & (y0 < 64), vy1 = (y1 >= 0) & (y1 < 64);
    float w00 = (vx0 & vy0) ? wx0 * wy0 : 0.0f;
    float w10 = (vx1 & vy0) ? wx1 * wy0 : 0.0f;
    float w01 = (vx0 & vy1) ? wx0 * wy1 : 0.0f;
    float w11 = (vx1 & vy1) ? wx1 * wy1 : 0.0f;
    int cx0 = min(max(x0, 0), 63), cx1 = min(max(x1, 0), 63);
    int cy0 = min(max(y0, 0), 63), cy1 = min(max(y1, 0), 63);

    const size_t base = (size_t)b * 4096;
    const size_t r00 = (base + (size_t)(cy0 * 64 + cx0)) * 1024;
    const size_t r10 = (base + (size_t)(cy0 * 64 + cx1)) * 1024;
    const size_t r01 = (base + (size_t)(cy1 * 64 + cx0)) * 1024;
    const size_t r11 = (base + (size_t)(cy1 * 64 + cx1)) * 1024;

    const int c = lane * 8;

    // q row (bf16, interleaved in d_out at elem stride 1024) — streamed once
    const unsigned short* qrowb =
        (const unsigned short*)qo + ((size_t)(b * 4096 + n)) * 1024;
    u32x4 qu = __builtin_nontemporal_load((const u32x4*)(qrowb + c));
    float qv[8];
    #pragma unroll
    for (int t = 0; t < 4; ++t) {
        qv[2 * t]     = __uint_as_float(qu[t] << 16);
        qv[2 * t + 1] = __uint_as_float(qu[t] & 0xFFFF0000u);
    }

    float sk[8], sv[8];
    {
        uint4 u00k = *(const uint4*)(kvbf + r00 + c);
        uint4 u10k = *(const uint4*)(kvbf + r10 + c);
        uint4 u01k = *(const uint4*)(kvbf + r01 + c);
        uint4 u11k = *(const uint4*)(kvbf + r11 + c);
        uint4 u00v = *(const uint4*)(kvbf + r00 + 512 + c);
        uint4 u10v = *(const uint4*)(kvbf + r10 + 512 + c);
        uint4 u01v = *(const uint4*)(kvbf + r01 + 512 + c);
        uint4 u11v = *(const uint4*)(kvbf + r11 + 512 + c);
        const unsigned* p00k = (const unsigned*)&u00k;
        const unsigned* p10k = (const unsigned*)&u10k;
        const unsigned* p01k = (const unsigned*)&u01k;
        const unsigned* p11k = (const unsigned*)&u11k;
        const unsigned* p00v = (const unsigned*)&u00v;
        const unsigned* p10v = (const unsigned*)&u10v;
        const unsigned* p01v = (const unsigned*)&u01v;
        const unsigned* p11v = (const unsigned*)&u11v;
        #pragma unroll
        for (int t = 0; t < 4; ++t) {
            float a00 = __uint_as_float(p00k[t] << 16);
            float b00 = __uint_as_float(p00k[t] & 0xFFFF0000u);
            float a10 = __uint_as_float(p10k[t] << 16);
            float b10 = __uint_as_float(p10k[t] & 0xFFFF0000u);
            float a01 = __uint_as_float(p01k[t] << 16);
            float b01 = __uint_as_float(p01k[t] & 0xFFFF0000u);
            float a11 = __uint_as_float(p11k[t] << 16);
            float b11 = __uint_as_float(p11k[t] & 0xFFFF0000u);
            sk[2 * t]     = w00 * a00 + w10 * a10 + w01 * a01 + w11 * a11;
            sk[2 * t + 1] = w00 * b00 + w10 * b10 + w01 * b01 + w11 * b11;
            a00 = __uint_as_float(p00v[t] << 16);
            b00 = __uint_as_float(p00v[t] & 0xFFFF0000u);
            a10 = __uint_as_float(p10v[t] << 16);
            b10 = __uint_as_float(p10v[t] & 0xFFFF0000u);
            a01 = __uint_as_float(p01v[t] << 16);
            b01 = __uint_as_float(p01v[t] & 0xFFFF0000u);
            a11 = __uint_as_float(p11v[t] << 16);
            b11 = __uint_as_float(p11v[t] & 0xFFFF0000u);
            sv[2 * t]     = w00 * a00 + w10 * a10 + w01 * a01 + w11 * a11;
            sv[2 * t + 1] = w00 * b00 + w10 * b10 + w01 * b01 + w11 * b11;
        }
    }

    float score = 0.0f;
    #pragma unroll
    for (int t = 0; t < 8; ++t) score += qv[t] * sk[t];
    #pragma unroll
    for (int off = 32; off > 0; off >>= 1)
        score += __shfl_xor(score, off);

    const float sig = 1.0f / (1.0f + expf(-0.01f * score));
    float* orow = qo + ((size_t)(b * 4096 + n)) * 512;
    f32x4 oA, oB;
    oA[0] = sig * sv[0]; oA[1] = sig * sv[1]; oA[2] = sig * sv[2]; oA[3] = sig * sv[3];
    oB[0] = sig * sv[4]; oB[1] = sig * sv[5]; oB[2] = sig * sv[6]; oB[3] = sig * sv[7];
    // output is never re-read: nontemporal stores keep L2/L3 for kv gathers
    __builtin_nontemporal_store(oA, (f32x4*)(orow + c));
    __builtin_nontemporal_store(oB, (f32x4*)(orow + c + 4));
}

extern "C" void kernel_launch(void* const* d_in, const int* in_sizes, int n_in,
                              void* d_out, int out_size, void* d_ws, size_t ws_size,
                              hipStream_t stream)
{
    const float* x    = (const float*)d_in[0];
    const float* Wq   = (const float*)d_in[1];
    const float* bq   = (const float*)d_in[2];
    const float* Wk   = (const float*)d_in[3];
    const float* bk   = (const float*)d_in[4];
    const float* Wv   = (const float*)d_in[5];
    const float* bv   = (const float*)d_in[6];
    const float* avgs = (const float*)d_in[7];
    const float* stds = (const float*)d_in[8];
    const float* nx   = (const float*)d_in[9];
    const float* ny   = (const float*)d_in[10];
    const int* img_ids = (const int*)d_in[11];

    float* out = (float*)d_out;

    unsigned short* xbf  = (unsigned short*)d_ws;           // 67.1 MB
    unsigned short* wbf  = xbf + (size_t)65536 * 512;       // 1.57 MB
    unsigned short* kvbf = wbf + (size_t)1536 * 512;        // 134 MB ([k|v] rows)

    cvt_all<<<16768, 256, 0, stream>>>(x, Wq, Wk, Wv, xbf, wbf);

    qkv_gemm<<<1536, 512, 0, stream>>>(xbf, wbf, bq, bk, bv,
                                       (unsigned short*)d_out, kvbf);

    sample_attn<<<16384, 256, 0, stream>>>(out, kvbf, avgs, stds, nx, ny, img_ids);
}